// Round 5
// baseline (361.495 us; speedup 1.0000x reference)
//
#include <hip/hip_runtime.h>

#define B_   2
#define NC_  256
#define CN_  256
#define K_   16
#define DN_  64
#define G_   8
#define HM_  128
#define F3_  192

typedef unsigned short u16;
typedef short v8s __attribute__((ext_vector_type(8)));
typedef float v4f __attribute__((ext_vector_type(4)));

// LDS (static, 79,872 B -> 2 blocks/CU):
//   hb      [256][68] bf16 = 34816   (h staged bf16; gather source + m1/s1 A-frags)
//   am      [256][68] bf16 = 34816   (agg, then msg; float reuse for pooled at tail)
//   scratch [128][40] bf16 = 10240   (K=32 mh/sh chunks; wave-private rows; f32 sums at tail)
//
// d_ws: bf16 weights (1 MB): mw1b[196608] mw2b[+196608] sw1b[+262144] sw2b[+458752]

__device__ __forceinline__ u16 f2b(float f) {
    unsigned v; __builtin_memcpy(&v, &f, 4);
    v = v + 0x7fffu + ((v >> 16) & 1u);   // RNE
    return (u16)(v >> 16);
}
__device__ __forceinline__ float asf(unsigned v) {
    float f; __builtin_memcpy(&f, &v, 4); return f;
}
__device__ __forceinline__ v8s cvt8(const float* p) {
    float4 a = *(const float4*)p, b = *(const float4*)(p + 4);
    v8s r;
    r[0] = (short)f2b(a.x); r[1] = (short)f2b(a.y); r[2] = (short)f2b(a.z); r[3] = (short)f2b(a.w);
    r[4] = (short)f2b(b.x); r[5] = (short)f2b(b.y); r[6] = (short)f2b(b.z); r[7] = (short)f2b(b.w);
    return r;
}
// 16-byte logical load from 8B-aligned LDS (stride-68 rows): two ds_read_b64
__device__ __forceinline__ v8s ld8(const u16* p) {
    uint2 a = *(const uint2*)p;
    uint2 b = *(const uint2*)(p + 4);
    v8s r;
    __builtin_memcpy(&r, &a, 8);
    __builtin_memcpy((char*)&r + 8, &b, 8);
    return r;
}
__device__ __forceinline__ float gelu_t(float x) {
    // jax.nn.gelu approximate=True: x*sigmoid(2*k0*x*(1+k1*x^2))
    float u = x * x;
    float t = 1.5957691216057308f * x * __builtin_fmaf(0.044715f, u, 1.0f);
    float e = __expf(-t);
    return x * __builtin_amdgcn_rcpf(1.0f + e);
}

__global__ __launch_bounds__(256) void cvt_w(
    const float* __restrict__ mw1, const float* __restrict__ mw2,
    const float* __restrict__ sw1, const float* __restrict__ sw2,
    u16* __restrict__ dst)
{
    int e = (blockIdx.x * 256 + threadIdx.x) * 4;   // 131072 threads * 4 = 524288
    const float* s; int off;
    if      (e < 196608) { s = mw1; off = e; }
    else if (e < 262144) { s = mw2; off = e - 196608; }
    else if (e < 458752) { s = sw1; off = e - 262144; }
    else                 { s = sw2; off = e - 458752; }
    float4 v = *(const float4*)(s + off);
    ushort4 o4;
    o4.x = f2b(v.x); o4.y = f2b(v.y); o4.z = f2b(v.z); o4.w = f2b(v.w);
    *(ushort4*)(dst + e) = o4;
}

__global__ __launch_bounds__(256, 2) void mg_main(
    const float* __restrict__ h,    const float* __restrict__ wconn,
    const float* __restrict__ ctx,  const float* __restrict__ nid,
    const u16* __restrict__ mw1b,   const float* __restrict__ mb1,
    const u16* __restrict__ mw2b,   const float* __restrict__ mb2,
    const u16* __restrict__ sw1b,   const float* __restrict__ sb1,
    const u16* __restrict__ sw2b,   const float* __restrict__ sb2,
    const float* __restrict__ dw1,  const float* __restrict__ db1,
    const float* __restrict__ dw2,  const float* __restrict__ db2,
    const int* __restrict__ conn,   const int* __restrict__ c2g,
    float* __restrict__ outf)
{
    const int bn   = blockIdx.x;          // 512 blocks: one per (b,cell)
    const int n    = bn & 255;
    const int tid  = threadIdx.x;
    const int wave = tid >> 6;
    const int lane = tid & 63;
    const int q    = lane >> 4;
    const int ln   = lane & 15;
    const int g    = c2g[n];

    __shared__ u16 hb[256 * 68];
    __shared__ u16 am[256 * 68];
    __shared__ u16 scratch[128 * 40];

    const size_t hbase = (size_t)bn * (CN_ * DN_);
    const size_t nbase = (size_t)n  * (CN_ * DN_);
    float* oH = outf + (size_t)bn * 16384;
    float* oM = outf + (size_t)8388608 + (size_t)bn * 16384;

    // ---------------- stage h -> hb (bf16) -----------------------------------
    {
        const float* hrow = h + hbase + (size_t)tid * DN_;
        u16* dst = hb + tid * 68;
#pragma unroll
        for (int i = 0; i < 16; ++i) {
            float4 v = *(const float4*)(hrow + i * 4);
            unsigned lo = (unsigned)f2b(v.x) | ((unsigned)f2b(v.y) << 16);
            unsigned hi = (unsigned)f2b(v.z) | ((unsigned)f2b(v.w) << 16);
            *(uint2*)(dst + i * 4) = make_uint2(lo, hi);
        }
    }
    __syncthreads();   // barrier #1: hb visible to all (gather reads any row)

    // ---------------- gather (VALU from LDS): agg = sum_k w * h[idx] ---------
    {
        const int half = lane & 1;
        const int rloc = lane >> 1;       // 0..31
        for (int pass = 0; pass < 2; ++pass) {
            const int r = wave * 64 + pass * 32 + rloc;   // wave-private row
            const int*   cp = conn  + n * 4096 + r * 16;
            const float* wp = wconn + (size_t)bn * 4096 + r * 16;
            int iv[16]; float wv[16];
#pragma unroll
            for (int k = 0; k < 16; ++k) { iv[k] = cp[k]; wv[k] = wp[k]; }
            float agg[32];
#pragma unroll
            for (int j = 0; j < 32; ++j) agg[j] = 0.0f;
#pragma unroll 4
            for (int k = 0; k < 16; ++k) {
                const u16* hp = hb + iv[k] * 68 + half * 32;
                float w = wv[k];
#pragma unroll
                for (int j = 0; j < 8; ++j) {
                    uint2 u = *(const uint2*)(hp + j * 4);
                    agg[j*4+0] = __builtin_fmaf(w, asf(u.x << 16),        agg[j*4+0]);
                    agg[j*4+1] = __builtin_fmaf(w, asf(u.x & 0xffff0000u),agg[j*4+1]);
                    agg[j*4+2] = __builtin_fmaf(w, asf(u.y << 16),        agg[j*4+2]);
                    agg[j*4+3] = __builtin_fmaf(w, asf(u.y & 0xffff0000u),agg[j*4+3]);
                }
            }
            u16* dst = am + r * 68 + half * 32;
#pragma unroll
            for (int j = 0; j < 8; ++j) {
                unsigned lo = (unsigned)f2b(agg[j*4+0]) | ((unsigned)f2b(agg[j*4+1]) << 16);
                unsigned hi = (unsigned)f2b(agg[j*4+2]) | ((unsigned)f2b(agg[j*4+3]) << 16);
                *(uint2*)(dst + j * 4) = make_uint2(lo, hi);
            }
        }
    }
    // no barrier: rows wave-private through the whole MLP chain

    const u16* w1m = mw1b + (size_t)g * HM_ * F3_;
    const u16* w2m = mw2b + (size_t)g * DN_ * HM_;
    const u16* w1s = sw1b + (size_t)g * HM_ * F3_;
    const u16* w2s = sw2b + (size_t)g * DN_ * HM_;
    v8s cfr0 = cvt8(ctx + (size_t)bn * DN_ +  0 + q * 8);
    v8s cfr1 = cvt8(ctx + (size_t)bn * DN_ + 32 + q * 8);

    float mpart[4] = {0,0,0,0};
    float hpart[4] = {0,0,0,0};

    for (int g2 = 0; g2 < 2; ++g2) {
        const int rb = wave * 64 + g2 * 32;   // this group's 32 rows

        // ===== m-phase: mh = gelu([h|agg|nid]@mw1^T+b), msg = mh@mw2^T+b =====
        v8s afr[2][6];
#pragma unroll
        for (int mi = 0; mi < 2; ++mi) {
            int rr = rb + mi * 16 + ln;
            afr[mi][0] = ld8(hb + rr * 68 +  0 + q * 8);
            afr[mi][1] = ld8(hb + rr * 68 + 32 + q * 8);
            afr[mi][2] = ld8(am + rr * 68 +  0 + q * 8);
            afr[mi][3] = ld8(am + rr * 68 + 32 + q * 8);
            afr[mi][4] = cvt8(nid + nbase + (size_t)rr * 64 +  0 + q * 8);
            afr[mi][5] = cvt8(nid + nbase + (size_t)rr * 64 + 32 + q * 8);
        }
        v4f macc[2][4];
#pragma unroll
        for (int mi = 0; mi < 2; ++mi)
#pragma unroll
            for (int nt = 0; nt < 4; ++nt) macc[mi][nt] = (v4f){0,0,0,0};

#pragma unroll
        for (int kc = 0; kc < 4; ++kc) {
#pragma unroll
            for (int t2 = 0; t2 < 2; ++t2) {
                int nt = kc * 2 + t2;
                float b1v = mb1[g * HM_ + nt * 16 + ln];
                v4f acc[2] = {{0,0,0,0},{0,0,0,0}};
#pragma unroll
                for (int ks = 0; ks < 6; ++ks) {
                    v8s bf = *(const v8s*)(w1m + (nt * 16 + ln) * F3_ + ks * 32 + q * 8);
#pragma unroll
                    for (int mi = 0; mi < 2; ++mi)
                        acc[mi] = __builtin_amdgcn_mfma_f32_16x16x32_bf16(afr[mi][ks], bf, acc[mi], 0, 0, 0);
                }
#pragma unroll
                for (int mi = 0; mi < 2; ++mi)
#pragma unroll
                    for (int r = 0; r < 4; ++r)
                        scratch[(wave * 32 + mi * 16 + q * 4 + r) * 40 + t2 * 16 + ln] =
                            f2b(gelu_t(acc[mi][r] + b1v));
            }
            // m2 partial over this K=32 chunk
            v8s as2[2];
#pragma unroll
            for (int mi = 0; mi < 2; ++mi)
                as2[mi] = *(const v8s*)(scratch + (wave * 32 + mi * 16 + ln) * 40 + q * 8);
#pragma unroll
            for (int nt = 0; nt < 4; ++nt) {
                v8s bf = *(const v8s*)(w2m + (nt * 16 + ln) * HM_ + kc * 32 + q * 8);
#pragma unroll
                for (int mi = 0; mi < 2; ++mi)
                    macc[mi][nt] = __builtin_amdgcn_mfma_f32_16x16x32_bf16(as2[mi], bf, macc[mi][nt], 0, 0, 0);
            }
        }
        // finalize msg: write am (bf16) + oM (f32) + pooled partial
#pragma unroll
        for (int nt = 0; nt < 4; ++nt) {
            float bb = mb2[g * DN_ + nt * 16 + ln];
            int d = nt * 16 + ln;
#pragma unroll
            for (int mi = 0; mi < 2; ++mi)
#pragma unroll
                for (int r = 0; r < 4; ++r) {
                    int rr = rb + mi * 16 + q * 4 + r;
                    float mv = macc[mi][nt][r] + bb;
                    am[rr * 68 + d] = f2b(mv);
                    oM[(size_t)rr * 64 + d] = mv;
                    mpart[nt] += mv;
                }
        }

        // ===== s-phase: sh = gelu([h|msg|ctx]@sw1^T+b), h_new = h + sh@sw2^T+b =====
        v8s mfr[2][2];
#pragma unroll
        for (int mi = 0; mi < 2; ++mi) {
            int rr = rb + mi * 16 + ln;
            mfr[mi][0] = ld8(am + rr * 68 +  0 + q * 8);
            mfr[mi][1] = ld8(am + rr * 68 + 32 + q * 8);
        }
        v4f sacc2[2][4];
#pragma unroll
        for (int mi = 0; mi < 2; ++mi)
#pragma unroll
            for (int nt = 0; nt < 4; ++nt) sacc2[mi][nt] = (v4f){0,0,0,0};

#pragma unroll
        for (int kc = 0; kc < 4; ++kc) {
#pragma unroll
            for (int t2 = 0; t2 < 2; ++t2) {
                int nt = kc * 2 + t2;
                float b1v = sb1[g * HM_ + nt * 16 + ln];
                v4f acc[2] = {{0,0,0,0},{0,0,0,0}};
#pragma unroll
                for (int ks = 0; ks < 6; ++ks) {
                    v8s bf = *(const v8s*)(w1s + (nt * 16 + ln) * F3_ + ks * 32 + q * 8);
                    v8s aa;
#pragma unroll
                    for (int mi = 0; mi < 2; ++mi) {
                        if      (ks < 2) aa = afr[mi][ks];        // h
                        else if (ks < 4) aa = mfr[mi][ks - 2];    // msg
                        else             aa = (ks == 4) ? cfr0 : cfr1;  // ctx bcast
                        acc[mi] = __builtin_amdgcn_mfma_f32_16x16x32_bf16(aa, bf, acc[mi], 0, 0, 0);
                    }
                }
#pragma unroll
                for (int mi = 0; mi < 2; ++mi)
#pragma unroll
                    for (int r = 0; r < 4; ++r)
                        scratch[(wave * 32 + mi * 16 + q * 4 + r) * 40 + t2 * 16 + ln] =
                            f2b(gelu_t(acc[mi][r] + b1v));
            }
            v8s as2[2];
#pragma unroll
            for (int mi = 0; mi < 2; ++mi)
                as2[mi] = *(const v8s*)(scratch + (wave * 32 + mi * 16 + ln) * 40 + q * 8);
#pragma unroll
            for (int nt = 0; nt < 4; ++nt) {
                v8s bf = *(const v8s*)(w2s + (nt * 16 + ln) * HM_ + kc * 32 + q * 8);
#pragma unroll
                for (int mi = 0; mi < 2; ++mi)
                    sacc2[mi][nt] = __builtin_amdgcn_mfma_f32_16x16x32_bf16(as2[mi], bf, sacc2[mi][nt], 0, 0, 0);
            }
        }
        // finalize h_new: f32 residual from global
#pragma unroll
        for (int nt = 0; nt < 4; ++nt) {
            float bb = sb2[g * DN_ + nt * 16 + ln];
            int d = nt * 16 + ln;
#pragma unroll
            for (int mi = 0; mi < 2; ++mi)
#pragma unroll
                for (int r = 0; r < 4; ++r) {
                    int rr = rb + mi * 16 + q * 4 + r;
                    float hv = h[hbase + (size_t)rr * 64 + d];
                    float hn = hv + sacc2[mi][nt][r] + bb;
                    oH[(size_t)rr * 64 + d] = hn;
                    hpart[nt] += hn;
                }
        }
    }

    // ---------------- per-wave pooled partials into scratch (f32) ------------
    {
        float* sf = (float*)scratch;   // wave w slice at sf[w*640 ...] (wave-private)
#pragma unroll
        for (int nt = 0; nt < 4; ++nt) {
            float hsv = hpart[nt];
            hsv += __shfl_xor(hsv, 16);
            hsv += __shfl_xor(hsv, 32);
            float msv = mpart[nt];
            msv += __shfl_xor(msv, 16);
            msv += __shfl_xor(msv, 32);
            if (q == 0) {
                sf[wave * 640 +      nt * 16 + ln] = hsv;
                sf[wave * 640 + 64 + nt * 16 + ln] = msv;
            }
        }
    }
    __syncthreads();   // barrier #2: all partials + outputs done

    // ---------------- pooled means + mod MLP (f32) ---------------------------
    float* sf  = (float*)scratch;
    float* plf = (float*)am;           // pooled[128]; r1 at plf[128..191]
    if (tid < 128) {
        int off = (tid < 64) ? (tid) : (64 + (tid - 64));
        float s = sf[0 * 640 + off] + sf[1 * 640 + off] + sf[2 * 640 + off] + sf[3 * 640 + off];
        plf[tid] = s * (1.0f / 256.0f);
    }
    __syncthreads();   // barrier #3: pooled ready

    float acc = 0.0f;
    if (tid < 128) {
        int col = tid & 63, fh = tid >> 6;
        if (fh == 0) acc = db1[n * 64 + col];
        const float* w1p = dw1 + (size_t)n * 8192;   // [128][64]
        for (int f = fh * 64; f < fh * 64 + 64; ++f)
            acc = __builtin_fmaf(plf[f], w1p[f * 64 + col], acc);
        if (fh == 1) plf[128 + col] = acc;
    }
    __syncthreads();   // barrier #4: r1 ready

    if (tid < 64) {
        float ph = gelu_t(acc + plf[128 + tid]);
        float part[5];
#pragma unroll
        for (int o = 0; o < 5; ++o) part[o] = ph * dw2[(size_t)(n * 64 + tid) * 5 + o];
#pragma unroll
        for (int off = 32; off > 0; off >>= 1)
#pragma unroll
            for (int o = 0; o < 5; ++o) part[o] += __shfl_down(part[o], off);
        if (tid == 0) {
#pragma unroll
            for (int o = 0; o < 5; ++o)
                outf[(size_t)16777216 + bn * 5 + o] = part[o] + db2[n * 5 + o];
        }
    }
}

extern "C" void kernel_launch(void* const* d_in, const int* in_sizes, int n_in,
                              void* d_out, int out_size, void* d_ws, size_t ws_size,
                              hipStream_t stream) {
    const float* h     = (const float*)d_in[0];
    const float* wconn = (const float*)d_in[1];
    const float* ctx   = (const float*)d_in[2];
    const float* nid   = (const float*)d_in[3];
    const float* mw1   = (const float*)d_in[4];
    const float* mb1   = (const float*)d_in[5];
    const float* mw2   = (const float*)d_in[6];
    const float* mb2   = (const float*)d_in[7];
    const float* sw1   = (const float*)d_in[8];
    const float* sb1   = (const float*)d_in[9];
    const float* sw2   = (const float*)d_in[10];
    const float* sb2   = (const float*)d_in[11];
    const float* dw1   = (const float*)d_in[12];
    const float* db1   = (const float*)d_in[13];
    const float* dw2   = (const float*)d_in[14];
    const float* db2   = (const float*)d_in[15];
    const int* conn    = (const int*)d_in[16];
    const int* c2g     = (const int*)d_in[17];
    float* outf  = (float*)d_out;
    u16*   wb    = (u16*)d_ws;   // bf16 weight copies (1 MB)

    cvt_w<<<512, 256, 0, stream>>>(mw1, mw2, sw1, sw2, wb);
    mg_main<<<512, 256, 0, stream>>>(h, wconn, ctx, nid,
                                     wb,           mb1,
                                     wb + 196608,  mb2,
                                     wb + 262144,  sb1,
                                     wb + 458752,  sb2,
                                     dw1, db1, dw2, db2,
                                     conn, c2g, outf);
}